// Round 1
// baseline (673.078 us; speedup 1.0000x reference)
//
#include <hip/hip_runtime.h>
#include <hip/hip_bf16.h>

// NT-Xent (CLIP) loss, N=16384 D=256 fp32 in, 3 fp32 out.
// loss_vu = mean_i( log(sum_j exp(sim_ij)) - sim_ii ), sim = (v̂·û^T)/T
// Logits bounded by 1/T=14.29 -> no max subtraction needed for exp stability.

#define D_DIM 256
#define BM 128
#define BN 128
#define BK 64

constexpr float INV_T = 1.0f / 0.07f;

typedef __bf16 bf16x8 __attribute__((ext_vector_type(8)));
typedef float f32x4 __attribute__((ext_vector_type(4)));

// ---------------------------------------------------------------------------
// Kernel 1: L2-normalize both feature sets (fp32 -> bf16), accumulate
//           sum_i v̂_i·û_i (fp32, exact diag term) into *diag.
// One block (256 threads) per row pair.
// ---------------------------------------------------------------------------
__global__ __launch_bounds__(256) void normalize_kernel(
    const float* __restrict__ img, const float* __restrict__ txt,
    __hip_bfloat16* __restrict__ Vb, __hip_bfloat16* __restrict__ Ub,
    float* __restrict__ diag) {
  const int row = blockIdx.x;
  const int t = threadIdx.x;
  const size_t idx = (size_t)row * D_DIM + t;
  const float iv = img[idx];
  const float tv = txt[idx];

  float a = iv * iv, b = tv * tv;
#pragma unroll
  for (int off = 1; off < 64; off <<= 1) {
    a += __shfl_xor(a, off, 64);
    b += __shfl_xor(b, off, 64);
  }
  __shared__ float sh[12];
  const int w = t >> 6, lane = t & 63;
  if (lane == 0) { sh[w] = a; sh[4 + w] = b; }
  __syncthreads();
  a = sh[0] + sh[1] + sh[2] + sh[3];
  b = sh[4] + sh[5] + sh[6] + sh[7];
  const float si = 1.0f / fmaxf(sqrtf(a), 1e-8f);
  const float st = 1.0f / fmaxf(sqrtf(b), 1e-8f);
  const float v = iv * si;
  const float u = tv * st;
  Vb[idx] = __float2bfloat16(v);
  Ub[idx] = __float2bfloat16(u);

  float d = v * u;  // fp32 diag contribution (cosine, pre-/T)
#pragma unroll
  for (int off = 1; off < 64; off <<= 1) d += __shfl_xor(d, off, 64);
  if (lane == 0) sh[8 + w] = d;
  __syncthreads();
  if (t == 0) atomicAdd(diag, sh[8] + sh[9] + sh[10] + sh[11]);
}

// ---------------------------------------------------------------------------
// Kernel 2: tiled bf16 MFMA GEMM over sim = V·U^T, online exp-sum per row
//           and per column. 128x128 tile per block, 4 waves of 64x64.
// A-frag layout (16x16x32 bf16): A[m=lane&15][k=quad*8+j]
// B-frag (= U row-major, since sim = V·U^T): B[k=quad*8+j][n=lane&15]
// C/D layout: col=lane&15, row=quad*4+reg  (m89/m91-verified)
// ---------------------------------------------------------------------------
__global__ __launch_bounds__(256) void gemm_lse_kernel(
    const __hip_bfloat16* __restrict__ V, const __hip_bfloat16* __restrict__ U,
    float* __restrict__ rowsum, float* __restrict__ colsum) {
  __shared__ __align__(16) unsigned short As[BM * BK];  // 16 KB
  __shared__ __align__(16) unsigned short Bs[BN * BK];  // 16 KB

  const int tid = threadIdx.x;
  const int lane = tid & 63;
  const int wave = tid >> 6;
  const int wm = wave >> 1;   // wave row (0..1)
  const int wn = wave & 1;    // wave col (0..1)
  const int quad = lane >> 4;
  const int l15 = lane & 15;
  const int ibase = blockIdx.y * BM;
  const int jbase = blockIdx.x * BN;

  f32x4 acc[4][4] = {};

  for (int kk = 0; kk < D_DIM; kk += BK) {
    // Stage A and B tiles: 1024 x 16B chunks each; 4 chunks/thread each.
#pragma unroll
    for (int q = 0; q < 4; ++q) {
      const int chunk = q * 256 + tid;  // [0,1024)
      const int row = chunk >> 3;       // 8 x 16B per 64-col row
      const int c8 = chunk & 7;
      const uint4 va = *reinterpret_cast<const uint4*>(
          &V[(size_t)(ibase + row) * D_DIM + kk + c8 * 8]);
      const uint4 vb = *reinterpret_cast<const uint4*>(
          &U[(size_t)(jbase + row) * D_DIM + kk + c8 * 8]);
      *reinterpret_cast<uint4*>(&As[row * BK + c8 * 8]) = va;
      *reinterpret_cast<uint4*>(&Bs[row * BK + c8 * 8]) = vb;
    }
    __syncthreads();

#pragma unroll
    for (int ks = 0; ks < BK; ks += 32) {
      bf16x8 af[4], bfr[4];
#pragma unroll
      for (int mi = 0; mi < 4; ++mi)
        af[mi] = *reinterpret_cast<const bf16x8*>(
            &As[(wm * 64 + mi * 16 + l15) * BK + ks + quad * 8]);
#pragma unroll
      for (int ni = 0; ni < 4; ++ni)
        bfr[ni] = *reinterpret_cast<const bf16x8*>(
            &Bs[(wn * 64 + ni * 16 + l15) * BK + ks + quad * 8]);
#pragma unroll
      for (int mi = 0; mi < 4; ++mi)
#pragma unroll
        for (int ni = 0; ni < 4; ++ni)
          acc[mi][ni] = __builtin_amdgcn_mfma_f32_16x16x32_bf16(
              af[mi], bfr[ni], acc[mi][ni], 0, 0, 0);
    }
    __syncthreads();
  }

  // ---- epilogue: exp + row/col reduction ----
  // acc[mi][ni][r] is sim element (row = wm*64+mi*16+quad*4+r,
  //                                col = wn*64+ni*16+l15) before /T scale.
#pragma unroll
  for (int mi = 0; mi < 4; ++mi)
#pragma unroll
    for (int ni = 0; ni < 4; ++ni)
#pragma unroll
      for (int r = 0; r < 4; ++r)
        acc[mi][ni][r] = __expf(acc[mi][ni][r] * INV_T);

  // Reuse As as fp32 scratch: rowbuf[128], colbuf[128].
  float* rowbuf = reinterpret_cast<float*>(As);
  float* colbuf = rowbuf + BM;
  reinterpret_cast<float*>(As)[tid] = 0.0f;  // zero 256 floats
  __syncthreads();

  // Row sums: sum over this wave's 64 columns, result lands on l15==0 lanes.
#pragma unroll
  for (int mi = 0; mi < 4; ++mi) {
#pragma unroll
    for (int r = 0; r < 4; ++r) {
      float rs = acc[mi][0][r] + acc[mi][1][r] + acc[mi][2][r] + acc[mi][3][r];
      rs += __shfl_xor(rs, 1, 64);
      rs += __shfl_xor(rs, 2, 64);
      rs += __shfl_xor(rs, 4, 64);
      rs += __shfl_xor(rs, 8, 64);
      if (l15 == 0)
        atomicAdd(&rowbuf[wm * 64 + mi * 16 + quad * 4 + r], rs);
    }
  }
  // Col sums: sum over this wave's 64 rows, result lands on lanes 0..15.
#pragma unroll
  for (int ni = 0; ni < 4; ++ni) {
    float cs = 0.0f;
#pragma unroll
    for (int mi = 0; mi < 4; ++mi)
      cs += acc[mi][ni][0] + acc[mi][ni][1] + acc[mi][ni][2] + acc[mi][ni][3];
    cs += __shfl_xor(cs, 16, 64);
    cs += __shfl_xor(cs, 32, 64);
    if (lane < 16)
      atomicAdd(&colbuf[wn * 64 + ni * 16 + l15], cs);
  }
  __syncthreads();

  if (tid < BM)
    atomicAdd(&rowsum[ibase + tid], rowbuf[tid]);
  else
    atomicAdd(&colsum[jbase + tid - BM], colbuf[tid - BM]);
}

// ---------------------------------------------------------------------------
// Kernel 3: finalize — mean(log(rowsum)), mean(log(colsum)), combine w/ diag.
// ---------------------------------------------------------------------------
__global__ __launch_bounds__(1024) void finalize_kernel(
    const float* __restrict__ rowsum, const float* __restrict__ colsum,
    const float* __restrict__ diag, float* __restrict__ out, int n) {
  __shared__ float sh[32];
  float sr = 0.0f, sc = 0.0f;
  for (int i = threadIdx.x; i < n; i += 1024) {
    sr += logf(rowsum[i]);
    sc += logf(colsum[i]);
  }
#pragma unroll
  for (int off = 1; off < 64; off <<= 1) {
    sr += __shfl_xor(sr, off, 64);
    sc += __shfl_xor(sc, off, 64);
  }
  const int w = threadIdx.x >> 6, lane = threadIdx.x & 63;
  if (lane == 0) { sh[w] = sr; sh[16 + w] = sc; }
  __syncthreads();
  if (threadIdx.x == 0) {
    float tr = 0.0f, tc = 0.0f;
#pragma unroll
    for (int i = 0; i < 16; ++i) { tr += sh[i]; tc += sh[16 + i]; }
    const float invN = 1.0f / (float)n;
    const float dm = diag[0] * INV_T * invN;   // mean diag logit
    const float lvu = tr * invN - dm;
    const float luv = tc * invN - dm;
    out[0] = 0.5f * lvu + 0.5f * luv;  // WEIGHT = 0.5
    out[1] = lvu;
    out[2] = luv;
  }
}

extern "C" void kernel_launch(void* const* d_in, const int* in_sizes, int n_in,
                              void* d_out, int out_size, void* d_ws, size_t ws_size,
                              hipStream_t stream) {
  const float* img = (const float*)d_in[0];
  const float* txt = (const float*)d_in[1];
  float* out = (float*)d_out;
  const int N = in_sizes[0] / D_DIM;  // 16384

  char* ws = (char*)d_ws;
  __hip_bfloat16* Vb = (__hip_bfloat16*)ws;
  __hip_bfloat16* Ub = (__hip_bfloat16*)(ws + (size_t)N * D_DIM * 2);
  float* rowsum = (float*)(ws + (size_t)N * D_DIM * 4);
  float* colsum = rowsum + N;
  float* diag = colsum + N;

  // zero rowsum, colsum, diag (ws is poisoned 0xAA before every launch)
  hipMemsetAsync(rowsum, 0, (size_t)(2 * N + 16) * sizeof(float), stream);

  normalize_kernel<<<N, 256, 0, stream>>>(img, txt, Vb, Ub, diag);

  dim3 grid(N / BN, N / BM);
  gemm_lse_kernel<<<grid, 256, 0, stream>>>(Vb, Ub, rowsum, colsum);

  finalize_kernel<<<1, 1024, 0, stream>>>(rowsum, colsum, diag, out, N);
}

// Round 2
// 289.732 us; speedup vs baseline: 2.3231x; 2.3231x over previous
//
#include <hip/hip_runtime.h>
#include <hip/hip_bf16.h>

// NT-Xent (CLIP) loss, N=16384 D=256 fp32 in, 3 fp32 out.
// loss_vu = mean_i( log(sum_j exp(sim_ij)) - sim_ii ), sim = (v̂·û^T)/T
// Logits bounded by 1/T=14.29 -> no max subtraction needed for exp stability.
//
// R2: XOR-swizzled LDS (kills 16-way bank conflicts on frag reads),
//     diag via per-row array instead of single-address atomic.

#define D_DIM 256
#define BM 128
#define BN 128
#define BK 64

constexpr float INV_T = 1.0f / 0.07f;

typedef __bf16 bf16x8 __attribute__((ext_vector_type(8)));
typedef float f32x4 __attribute__((ext_vector_type(4)));

// ---------------------------------------------------------------------------
// Kernel 1: L2-normalize (fp32 -> bf16), one WAVE per row (4 rows/block).
//           Writes per-row diag contribution v̂_i·û_i to diagarr (no atomic).
// ---------------------------------------------------------------------------
__global__ __launch_bounds__(256) void normalize_kernel(
    const float* __restrict__ img, const float* __restrict__ txt,
    __hip_bfloat16* __restrict__ Vb, __hip_bfloat16* __restrict__ Ub,
    float* __restrict__ diagarr) {
  const int wave = threadIdx.x >> 6;
  const int lane = threadIdx.x & 63;
  const int row = blockIdx.x * 4 + wave;
  const size_t base = (size_t)row * D_DIM + lane * 4;

  const float4 iv = *reinterpret_cast<const float4*>(&img[base]);
  const float4 tv = *reinterpret_cast<const float4*>(&txt[base]);

  float a = iv.x * iv.x + iv.y * iv.y + iv.z * iv.z + iv.w * iv.w;
  float b = tv.x * tv.x + tv.y * tv.y + tv.z * tv.z + tv.w * tv.w;
#pragma unroll
  for (int off = 1; off < 64; off <<= 1) {
    a += __shfl_xor(a, off, 64);
    b += __shfl_xor(b, off, 64);
  }
  const float si = 1.0f / fmaxf(sqrtf(a), 1e-8f);
  const float st = 1.0f / fmaxf(sqrtf(b), 1e-8f);
  const float4 v = {iv.x * si, iv.y * si, iv.z * si, iv.w * si};
  const float4 u = {tv.x * st, tv.y * st, tv.z * st, tv.w * st};

  __hip_bfloat16 vb4[4] = {__float2bfloat16(v.x), __float2bfloat16(v.y),
                           __float2bfloat16(v.z), __float2bfloat16(v.w)};
  __hip_bfloat16 ub4[4] = {__float2bfloat16(u.x), __float2bfloat16(u.y),
                           __float2bfloat16(u.z), __float2bfloat16(u.w)};
  *reinterpret_cast<uint2*>(&Vb[base]) = *reinterpret_cast<uint2*>(vb4);
  *reinterpret_cast<uint2*>(&Ub[base]) = *reinterpret_cast<uint2*>(ub4);

  float d = v.x * u.x + v.y * u.y + v.z * u.z + v.w * u.w;
#pragma unroll
  for (int off = 1; off < 64; off <<= 1) d += __shfl_xor(d, off, 64);
  if (lane == 0) diagarr[row] = d;
}

// ---------------------------------------------------------------------------
// Kernel 2: tiled bf16 MFMA GEMM over sim = V·U^T, online exp-sum per row
//           and per column. 128x128 tile/block, 4 waves of 64x64.
// LDS layout XOR-swizzled: 16B chunk c8 of row r stored at chunk (c8 ^ (r&7)).
//   - staging writes: per wave, rows l>>3 (0..7) x chunks l&7 -> p=c8^row
//     spans 0..7 per row-group -> all 32 banks, conflict-free.
//   - frag reads: 16 lanes read rows base+l15 at chunk c8a -> p=c8a^(l15&7)
//     spans 0..7 per 8 lanes -> 2 lanes/bank = free (m136).
// A-frag (16x16x32): A[m=lane&15][k=quad*8+j]; B symmetric (U row-major).
// C/D: col=lane&15, row=quad*4+reg (m89/m91-verified).
// ---------------------------------------------------------------------------
__global__ __launch_bounds__(256) void gemm_lse_kernel(
    const __hip_bfloat16* __restrict__ V, const __hip_bfloat16* __restrict__ U,
    float* __restrict__ rowsum, float* __restrict__ colsum) {
  __shared__ __align__(16) unsigned short As[BM * BK];  // 16 KB
  __shared__ __align__(16) unsigned short Bs[BN * BK];  // 16 KB

  const int tid = threadIdx.x;
  const int lane = tid & 63;
  const int wave = tid >> 6;
  const int wm = wave >> 1;   // wave row (0..1)
  const int wn = wave & 1;    // wave col (0..1)
  const int quad = lane >> 4;
  const int l15 = lane & 15;
  const int sw = l15 & 7;     // read-swizzle factor (= frag row & 7)
  const int ibase = blockIdx.y * BM;
  const int jbase = blockIdx.x * BN;

  f32x4 acc[4][4] = {};

  for (int kk = 0; kk < D_DIM; kk += BK) {
    // Stage A and B tiles: 1024 x 16B chunks each; 4 chunks/thread each.
#pragma unroll
    for (int q = 0; q < 4; ++q) {
      const int chunk = q * 256 + tid;  // [0,1024)
      const int row = chunk >> 3;       // 8 x 16B per 64-col row
      const int c8 = chunk & 7;
      const int dst = row * BK + (((c8 ^ (row & 7))) << 3);  // swizzled
      const uint4 va = *reinterpret_cast<const uint4*>(
          &V[(size_t)(ibase + row) * D_DIM + kk + c8 * 8]);
      const uint4 vb = *reinterpret_cast<const uint4*>(
          &U[(size_t)(jbase + row) * D_DIM + kk + c8 * 8]);
      *reinterpret_cast<uint4*>(&As[dst]) = va;
      *reinterpret_cast<uint4*>(&Bs[dst]) = vb;
    }
    __syncthreads();

#pragma unroll
    for (int ks = 0; ks < BK; ks += 32) {
      const int c8a = (ks >> 3) + quad;          // logical 16B chunk
      const int pc = ((c8a ^ sw) << 3);          // swizzled short offset
      bf16x8 af[4], bfr[4];
#pragma unroll
      for (int mi = 0; mi < 4; ++mi)
        af[mi] = *reinterpret_cast<const bf16x8*>(
            &As[(wm * 64 + mi * 16 + l15) * BK + pc]);
#pragma unroll
      for (int ni = 0; ni < 4; ++ni)
        bfr[ni] = *reinterpret_cast<const bf16x8*>(
            &Bs[(wn * 64 + ni * 16 + l15) * BK + pc]);
#pragma unroll
      for (int mi = 0; mi < 4; ++mi)
#pragma unroll
        for (int ni = 0; ni < 4; ++ni)
          acc[mi][ni] = __builtin_amdgcn_mfma_f32_16x16x32_bf16(
              af[mi], bfr[ni], acc[mi][ni], 0, 0, 0);
    }
    __syncthreads();
  }

  // ---- epilogue: exp + row/col reduction ----
  // acc[mi][ni][r]: row = wm*64+mi*16+quad*4+r, col = wn*64+ni*16+l15.
#pragma unroll
  for (int mi = 0; mi < 4; ++mi)
#pragma unroll
    for (int ni = 0; ni < 4; ++ni)
#pragma unroll
      for (int r = 0; r < 4; ++r)
        acc[mi][ni][r] = __expf(acc[mi][ni][r] * INV_T);

  // Reuse As as fp32 scratch: rowbuf[128], colbuf[128].
  float* rowbuf = reinterpret_cast<float*>(As);
  float* colbuf = rowbuf + BM;
  reinterpret_cast<float*>(As)[tid] = 0.0f;  // zero 256 floats
  __syncthreads();

  // Row sums: reduce across 16 cols (lanes quad*16..quad*16+15), then the
  // two wn halves meet in LDS.
#pragma unroll
  for (int mi = 0; mi < 4; ++mi) {
#pragma unroll
    for (int r = 0; r < 4; ++r) {
      float rs = acc[mi][0][r] + acc[mi][1][r] + acc[mi][2][r] + acc[mi][3][r];
      rs += __shfl_xor(rs, 1, 64);
      rs += __shfl_xor(rs, 2, 64);
      rs += __shfl_xor(rs, 4, 64);
      rs += __shfl_xor(rs, 8, 64);
      if (l15 == 0)
        atomicAdd(&rowbuf[wm * 64 + mi * 16 + quad * 4 + r], rs);
    }
  }
  // Col sums: reduce across 16 rows (quads), two wm halves meet in LDS.
#pragma unroll
  for (int ni = 0; ni < 4; ++ni) {
    float cs = 0.0f;
#pragma unroll
    for (int mi = 0; mi < 4; ++mi)
      cs += acc[mi][ni][0] + acc[mi][ni][1] + acc[mi][ni][2] + acc[mi][ni][3];
    cs += __shfl_xor(cs, 16, 64);
    cs += __shfl_xor(cs, 32, 64);
    if (lane < 16)
      atomicAdd(&colbuf[wn * 64 + ni * 16 + l15], cs);
  }
  __syncthreads();

  if (tid < BM)
    atomicAdd(&rowsum[ibase + tid], rowbuf[tid]);
  else
    atomicAdd(&colsum[jbase + tid - BM], colbuf[tid - BM]);
}

// ---------------------------------------------------------------------------
// Kernel 3: finalize — mean(log(rowsum)), mean(log(colsum)), mean(diag).
// ---------------------------------------------------------------------------
__global__ __launch_bounds__(1024) void finalize_kernel(
    const float* __restrict__ rowsum, const float* __restrict__ colsum,
    const float* __restrict__ diagarr, float* __restrict__ out, int n) {
  __shared__ float sh[48];
  float sr = 0.0f, sc = 0.0f, sd = 0.0f;
  for (int i = threadIdx.x; i < n; i += 1024) {
    sr += logf(rowsum[i]);
    sc += logf(colsum[i]);
    sd += diagarr[i];
  }
#pragma unroll
  for (int off = 1; off < 64; off <<= 1) {
    sr += __shfl_xor(sr, off, 64);
    sc += __shfl_xor(sc, off, 64);
    sd += __shfl_xor(sd, off, 64);
  }
  const int w = threadIdx.x >> 6, lane = threadIdx.x & 63;
  if (lane == 0) { sh[w] = sr; sh[16 + w] = sc; sh[32 + w] = sd; }
  __syncthreads();
  if (threadIdx.x == 0) {
    float tr = 0.0f, tc = 0.0f, td = 0.0f;
#pragma unroll
    for (int i = 0; i < 16; ++i) {
      tr += sh[i]; tc += sh[16 + i]; td += sh[32 + i];
    }
    const float invN = 1.0f / (float)n;
    const float dm = td * INV_T * invN;   // mean diag logit
    const float lvu = tr * invN - dm;
    const float luv = tc * invN - dm;
    out[0] = 0.5f * lvu + 0.5f * luv;  // WEIGHT = 0.5
    out[1] = lvu;
    out[2] = luv;
  }
}

extern "C" void kernel_launch(void* const* d_in, const int* in_sizes, int n_in,
                              void* d_out, int out_size, void* d_ws, size_t ws_size,
                              hipStream_t stream) {
  const float* img = (const float*)d_in[0];
  const float* txt = (const float*)d_in[1];
  float* out = (float*)d_out;
  const int N = in_sizes[0] / D_DIM;  // 16384

  char* ws = (char*)d_ws;
  __hip_bfloat16* Vb = (__hip_bfloat16*)ws;
  __hip_bfloat16* Ub = (__hip_bfloat16*)(ws + (size_t)N * D_DIM * 2);
  float* rowsum = (float*)(ws + (size_t)N * D_DIM * 4);
  float* colsum = rowsum + N;
  float* diagarr = colsum + N;

  // zero rowsum/colsum (ws is poisoned 0xAA before every launch)
  hipMemsetAsync(rowsum, 0, (size_t)(2 * N) * sizeof(float), stream);

  normalize_kernel<<<N / 4, 256, 0, stream>>>(img, txt, Vb, Ub, diagarr);

  dim3 grid(N / BN, N / BM);
  gemm_lse_kernel<<<grid, 256, 0, stream>>>(Vb, Ub, rowsum, colsum);

  finalize_kernel<<<1, 1024, 0, stream>>>(rowsum, colsum, diagarr, out, N);
}